// Round 1
// 3189.949 us; speedup vs baseline: 1.1159x; 1.1159x over previous
//
#include <hip/hip_runtime.h>

// T=512, B=64, D=H=1024, gates=4096
#define TT 512
#define NB 64
#define DD 1024
#define NG 4096

typedef __attribute__((ext_vector_type(8))) __bf16 bf16x8;
typedef __attribute__((ext_vector_type(4))) float f32x4;

// workspace layout (bytes) — unchanged from previous version
#define WC_OFF   0ul                       // bf16 [4096][2048]  = 16,777,216
#define HBUF_OFF 16777216ul                // bf16 [2][64][1024] = 262,144
#define BIAS_OFF (HBUF_OFF + 262144ul)     // f32  [4096]        = 16,384
#define CNT_OFF  (BIAS_OFF + 16384ul)      // int  [2048] flags  = 8,192
#define XBF_OFF  (CNT_OFF + 8192ul)        // bf16 x mirror      = 67,108,864
#define WS_FULL  (XBF_OFF + 67108864ul)

__device__ __forceinline__ unsigned short f2bf(float f) {
  unsigned int u = __float_as_uint(f);
  u += 0x7fffu + ((u >> 16) & 1u);   // round-to-nearest-even
  return (unsigned short)(u >> 16);
}

__global__ void prep_kernel(const float* __restrict__ x, const float* __restrict__ h0,
                            const float* __restrict__ w_ih, const float* __restrict__ b_ih,
                            const float* __restrict__ w_hh, const float* __restrict__ b_hh,
                            unsigned char* __restrict__ ws, int use_xbf) {
  unsigned short* Wc  = (unsigned short*)(ws + WC_OFF);
  unsigned short* hb  = (unsigned short*)(ws + HBUF_OFF);
  float* bias         = (float*)(ws + BIAS_OFF);
  int* cnt            = (int*)(ws + CNT_OFF);
  unsigned short* xbf = (unsigned short*)(ws + XBF_OFF);
  long tid = (long)blockIdx.x * blockDim.x + threadIdx.x;
  long stride = (long)gridDim.x * blockDim.x;
  // W_cat[r][k] = k<1024 ? w_ih[r][k] : w_hh[r][k-1024]  (bf16)
  for (long i = tid; i < (long)NG * 2048; i += stride) {
    int r = (int)(i >> 11), k = (int)(i & 2047);
    float v = (k < 1024) ? w_ih[(long)r * 1024 + k] : w_hh[(long)r * 1024 + (k - 1024)];
    Wc[i] = f2bf(v);
  }
  for (long i = tid; i < NG; i += stride) bias[i] = b_ih[i] + b_hh[i];
  for (long i = tid; i < NB * DD; i += stride) hb[65536 + i] = f2bf(h0[i]);  // h_{-1} -> buf1
  for (long i = tid; i < 4 * TT; i += stride) cnt[i] = 0;                    // epoch flags
  if (use_xbf) {
    for (long i = tid; i < (long)TT * NB * DD; i += stride) xbf[i] = f2bf(x[i]);
  }
}

#define MFMA16 __builtin_amdgcn_mfma_f32_16x16x32_bf16

// 256 wgs (1/CU): bg = blockIdx>>6 (16 batch rows), cg = blockIdx&63 (16 h-cols).
// 8 waves, each owns K-cols [wv*128, wv*128+128) of x AND of h (K=2048 total).
// Weights register-resident (32 x bf16x8 = 128 VGPR). h fragments loaded DIRECTLY
// to registers via device-scope (L3-coherent, cache-bypassing) u64 loads — no LDS
// staging. Sync: per-wg epoch flag (store-only release after vmcnt(0) drain of the
// u64 h-publish); each wave polls only its 8 producer wgs. One lgkm-only barrier
// per step (raw s_barrier: prefetch loads stay in flight across it). Wave 0 does
// the cell update (c in registers) and publishes h as 64 u64 atomic stores.
// Buffer-reuse safety: a wg publishes h_t (overwriting h_{t-2}) only after its
// barrier at step t, which requires all 8 of its waves to have passed their polls
// (collectively all 64 producers >= t), i.e. every wg published h_{t-1}, i.e.
// every wg finished reading h_{t-2}.
__launch_bounds__(512, 2)
__global__ void lstm_kernel(const float* __restrict__ x, const float* __restrict__ c0,
                            float* __restrict__ out, unsigned char* __restrict__ ws,
                            int use_xbf) {
  __shared__ __align__(16) float red[2][8][16][68];  // 69,632 B (double-buffered partials)
  __shared__ float bias_l[64];

  const unsigned short* Wc   = (const unsigned short*)(ws + WC_OFF);
  unsigned long long* hb64   = (unsigned long long*)(ws + HBUF_OFF);  // [2][64][256] u64
  const float* bias          = (const float*)(ws + BIAS_OFF);
  int* flags                 = (int*)(ws + CNT_OFF);   // [256 wgs][8-int pad]
  const unsigned short* xbf  = (const unsigned short*)(ws + XBF_OFF);

  const int tid = threadIdx.x;
  const int bg = blockIdx.x >> 6;
  const int cg = blockIdx.x & 63;
  const int m0 = bg << 4;           // batch base
  const int j0 = cg << 4;           // h-col base
  const int wv = tid >> 6;          // wave 0..7
  const int lane = tid & 63;
  const int ln = lane & 15;
  const int lq = lane >> 4;

  // ---- preload weights into registers (once): wx = x-half K-chunk, wh = h-half ----
  bf16x8 wx[16], wh[16];
  {
    const int kx = wv * 128 + lq * 8;
#pragma unroll
    for (int g = 0; g < 4; ++g) {   // g = gate
      const unsigned short* wp = Wc + (long)(g * 1024 + j0 + ln) * 2048 + kx;
#pragma unroll
      for (int ks = 0; ks < 4; ++ks) {
        wx[g * 4 + ks] = *reinterpret_cast<const bf16x8*>(wp + ks * 32);
        wh[g * 4 + ks] = *reinterpret_cast<const bf16x8*>(wp + 1024 + ks * 32);
      }
    }
  }
  if (tid < 64) bias_l[tid] = bias[(tid >> 4) * 1024 + j0 + (tid & 15)];

  // ---- reducer (wave 0): cell state in registers, 4 cells/lane ----
  const int mm = lane >> 2;              // row 0..15
  const int jj0 = (lane & 3) << 2;       // col 0,4,8,12
  float cr0 = 0.f, cr1 = 0.f, cr2 = 0.f, cr3 = 0.f;
  if (wv == 0) {
    const float4 cv = *(const float4*)(c0 + (long)(m0 + mm) * DD + j0 + jj0);
    cr0 = cv.x; cr1 = cv.y; cr2 = cv.z; cr3 = cv.w;
  }

  // ---- x fragment prefetch (registers, 1 step ahead) ----
  const long xbase = (long)(m0 + ln) * DD + wv * 128 + lq * 8;
  uint4 xcur[4];
  auto load_x = [&](int tt) {
    if (use_xbf) {
      const unsigned short* xp = xbf + (long)tt * (NB * DD) + xbase;
#pragma unroll
      for (int ks = 0; ks < 4; ++ks)
        xcur[ks] = *reinterpret_cast<const uint4*>(xp + ks * 32);
    } else {
      const float* xp = x + (long)tt * (NB * DD) + xbase;
#pragma unroll
      for (int ks = 0; ks < 4; ++ks) {
        float4 f0 = *reinterpret_cast<const float4*>(xp + ks * 32);
        float4 f1 = *reinterpret_cast<const float4*>(xp + ks * 32 + 4);
        uint4 pk;
        pk.x = (unsigned)f2bf(f0.x) | ((unsigned)f2bf(f0.y) << 16);
        pk.y = (unsigned)f2bf(f0.z) | ((unsigned)f2bf(f0.w) << 16);
        pk.z = (unsigned)f2bf(f1.x) | ((unsigned)f2bf(f1.y) << 16);
        pk.w = (unsigned)f2bf(f1.z) | ((unsigned)f2bf(f1.w) << 16);
        xcur[ks] = pk;
      }
    }
  };
  load_x(0);

  // my h K-chunk [wv*128, wv*128+128) is produced by wgs cg' in [wv*8, wv*8+8)
  const int fl0 = (bg * 64 + wv * 8 + (lane & 7)) * 8;   // flags padded to 32B/wg
  const int myflag = (bg * 64 + cg) * 8;
  const int hrow = (m0 + ln) * 256 + wv * 32 + lq * 2;   // u64 index within buffer

#pragma unroll 1
  for (int t = 0; t < TT; ++t) {
    const int rb = t & 1;

    // ---- wait for my 8 producers to have published h_{t-1} ----
    if (t > 0) {
      while (true) {
        int v = __hip_atomic_load(flags + fl0, __ATOMIC_RELAXED, __HIP_MEMORY_SCOPE_AGENT);
        if (__all(v >= t)) break;
        __builtin_amdgcn_s_sleep(1);
      }
    }
    asm volatile("" ::: "memory");   // no hoisting of h loads above the poll

    // ---- issue h fragment loads (device-scope u64, straight to registers) ----
    const unsigned long long* hp = hb64 + ((t + 1) & 1) * 16384 + hrow;
    unsigned long long hq[8];
#pragma unroll
    for (int ks = 0; ks < 4; ++ks) {
      hq[2 * ks]     = __hip_atomic_load(hp + ks * 8,     __ATOMIC_RELAXED, __HIP_MEMORY_SCOPE_AGENT);
      hq[2 * ks + 1] = __hip_atomic_load(hp + ks * 8 + 1, __ATOMIC_RELAXED, __HIP_MEMORY_SCOPE_AGENT);
    }

    // ---- x MFMAs (prefetched regs; hide h-load latency) ----
    f32x4 a0 = {0.f, 0.f, 0.f, 0.f}, a1 = a0, a2 = a0, a3 = a0;
#pragma unroll
    for (int ks = 0; ks < 4; ++ks) {
      bf16x8 af = __builtin_bit_cast(bf16x8, xcur[ks]);
      a0 = MFMA16(af, wx[ks],      a0, 0, 0, 0);
      a1 = MFMA16(af, wx[4 + ks],  a1, 0, 0, 0);
      a2 = MFMA16(af, wx[8 + ks],  a2, 0, 0, 0);
      a3 = MFMA16(af, wx[12 + ks], a3, 0, 0, 0);
    }
    // ---- prefetch x for t+1 (rides across the lgkm-only barrier) ----
    if (wv != 0 && t + 1 < TT) load_x(t + 1);

    // ---- h MFMAs ----
#pragma unroll
    for (int ks = 0; ks < 4; ++ks) {
      union { unsigned long long q[2]; bf16x8 v; } uu;
      uu.q[0] = hq[2 * ks]; uu.q[1] = hq[2 * ks + 1];
      a0 = MFMA16(uu.v, wh[ks],      a0, 0, 0, 0);
      a1 = MFMA16(uu.v, wh[4 + ks],  a1, 0, 0, 0);
      a2 = MFMA16(uu.v, wh[8 + ks],  a2, 0, 0, 0);
      a3 = MFMA16(uu.v, wh[12 + ks], a3, 0, 0, 0);
    }

    // ---- write partials (D layout: col=lane&15, row=(lane>>4)*4+r) ----
#pragma unroll
    for (int r = 0; r < 4; ++r) {
      float* rp = &red[rb][wv][lq * 4 + r][ln];
      rp[0] = a0[r]; rp[16] = a1[r]; rp[32] = a2[r]; rp[48] = a3[r];
    }

    // lgkm-only barrier: LDS partials visible, but vm prefetch stays in flight
    asm volatile("s_waitcnt lgkmcnt(0)" ::: "memory");
    __builtin_amdgcn_s_barrier();
    __builtin_amdgcn_sched_barrier(0);

    // ---- reduce + cell update + publish (wave 0 only) ----
    if (wv == 0) {
      __builtin_amdgcn_s_setprio(1);
      f32x4 s0 = *(const f32x4*)&bias_l[jj0];
      f32x4 s1 = *(const f32x4*)&bias_l[16 + jj0];
      f32x4 s2 = *(const f32x4*)&bias_l[32 + jj0];
      f32x4 s3 = *(const f32x4*)&bias_l[48 + jj0];
#pragma unroll
      for (int w = 0; w < 8; ++w) {
        const float* rp = &red[rb][w][mm][jj0];
        s0 += *(const f32x4*)(rp);
        s1 += *(const f32x4*)(rp + 16);
        s2 += *(const f32x4*)(rp + 32);
        s3 += *(const f32x4*)(rp + 48);
      }
      float cold[4] = {cr0, cr1, cr2, cr3};
      float hv[4], cn[4];
#pragma unroll
      for (int e = 0; e < 4; ++e) {
        float ig = 1.f / (1.f + __expf(-s0[e]));
        float fg = 1.f / (1.f + __expf(-s1[e]));
        float gg = 1.f - 2.f / (__expf(2.f * s2[e]) + 1.f);   // tanh
        float og = 1.f / (1.f + __expf(-s3[e]));
        float c2 = fg * cold[e] + ig * gg;
        cn[e] = c2;
        hv[e] = og * (1.f - 2.f / (__expf(2.f * c2) + 1.f));
      }
      cr0 = cn[0]; cr1 = cn[1]; cr2 = cn[2]; cr3 = cn[3];

      const long ho = (long)(m0 + mm) * 1024 + j0 + jj0;
      *(float4*)(out + (long)t * 65536 + ho) = make_float4(hv[0], hv[1], hv[2], hv[3]);
      if (t == TT - 1) {
        *(float4*)(out + (long)TT * 65536 + ho) = make_float4(hv[0], hv[1], hv[2], hv[3]);
        *(float4*)(out + (long)TT * 65536 + 65536 + ho) = make_float4(cn[0], cn[1], cn[2], cn[3]);
      }
      // publish h_t (one u64 = 4 bf16 per lane), then release flag
      unsigned long long hqo = (unsigned long long)f2bf(hv[0])
        | ((unsigned long long)f2bf(hv[1]) << 16)
        | ((unsigned long long)f2bf(hv[2]) << 32)
        | ((unsigned long long)f2bf(hv[3]) << 48);
      __hip_atomic_store(hb64 + rb * 16384 + (m0 + mm) * 256 + ((j0 + jj0) >> 2), hqo,
                         __ATOMIC_RELAXED, __HIP_MEMORY_SCOPE_AGENT);
      asm volatile("s_waitcnt vmcnt(0)" ::: "memory");   // h (and out) stores at coherence point
      if (lane == 0)
        __hip_atomic_store(flags + myflag, t + 1, __ATOMIC_RELAXED, __HIP_MEMORY_SCOPE_AGENT);
      __builtin_amdgcn_s_setprio(0);
      if (t + 1 < TT) load_x(t + 1);   // wave0 prefetches after release (keeps flag path clean)
    }
  }
}

extern "C" void kernel_launch(void* const* d_in, const int* in_sizes, int n_in,
                              void* d_out, int out_size, void* d_ws, size_t ws_size,
                              hipStream_t stream) {
  const float* x    = (const float*)d_in[0];
  const float* h0   = (const float*)d_in[1];
  const float* c0   = (const float*)d_in[2];
  const float* w_ih = (const float*)d_in[3];
  const float* b_ih = (const float*)d_in[4];
  const float* w_hh = (const float*)d_in[5];
  const float* b_hh = (const float*)d_in[6];
  float* out = (float*)d_out;
  unsigned char* ws = (unsigned char*)d_ws;
  int use_xbf = (ws_size >= WS_FULL) ? 1 : 0;

  hipLaunchKernelGGL(prep_kernel, dim3(2048), dim3(256), 0, stream,
                     x, h0, w_ih, b_ih, w_hh, b_hh, ws, use_xbf);

  void* args[] = { (void*)&x, (void*)&c0, (void*)&out, (void*)&ws, (void*)&use_xbf };
  hipLaunchCooperativeKernel(reinterpret_cast<void*>(lstm_kernel),
                             dim3(256), dim3(512), args, 0, stream);
}